// Round 11
// baseline (616.723 us; speedup 1.0000x reference)
//
#include <hip/hip_runtime.h>

#define N_NODES   100000
#define N_EDGES   1600000
#define WALK_LEN  16
#define OUT_DIM   8
#define N_PROBES  32

#define SCAN_BLK  256
#define NBLK      ((N_NODES + SCAN_BLK - 1) / SCAN_BLK)   // 391

// ---- LDS byte-counter build parameters ----
#define HB        128                      // histogram blocks per array (row/col)
#define SLICE     (N_EDGES / HB)           // 12500 edges per block (exact)
#define NWORDS    (N_NODES / 4)            // 25000 packed uints = 100 KB LDS
#define RB        ((NWORDS + 255) / 256)   // reduce blocks per half

// ---- adjacency padding: every list rounded up to multiple of 16 (burst) ----
#define BURST     16
#define DUMMY     N_NODES                  // dummy source row (always zero)
#define CSC_CAP   (N_EDGES + (BURST - 1) * N_NODES)   // 3.1M padded entries

// ---- gather grid + bijective XCD swizzle (nwg = 3125) ----
#define GGRID     ((N_NODES * 8) / 256)    // 3125 exact
#define GQ        (GGRID / 8)              // 390
#define GR        (GGRID % 8)              // 5

typedef _Float16 half4 __attribute__((ext_vector_type(4)));
typedef float float2v __attribute__((ext_vector_type(2)));

__device__ __forceinline__ int pad_burst(int x) { return (x + BURST - 1) & ~(BURST - 1); }

// ---------------- fused per-block byte-packed histograms: row -> partialR, col -> partialC ----
__global__ void hist2_kernel(const int* __restrict__ row, const int* __restrict__ col,
                             unsigned char* __restrict__ partialR,
                             unsigned char* __restrict__ partialC) {
    __shared__ unsigned int cnt[NWORDS];
    int blk = blockIdx.x;
    const int* arr = (blk < HB) ? row : col;
    unsigned char* partial = (blk < HB) ? partialR : partialC;
    int b = (blk < HB) ? blk : blk - HB;
    int t = threadIdx.x;                   // 1024 threads
    for (int i = t; i < NWORDS; i += 1024) cnt[i] = 0;
    __syncthreads();
    const int* a = arr + b * SLICE;
    for (int i = t; i < SLICE; i += 1024) {
        int v = a[i];
        atomicAdd(&cnt[v >> 2], 1u << ((v & 3) * 8));
    }
    __syncthreads();
    unsigned int* dst = (unsigned int*)(partial + (size_t)b * N_NODES);
    for (int i = t; i < NWORDS; i += 1024) dst[i] = cnt[i];
}

// ---------------- fused reduces: half A: outdeg->inv (packed dual counters); half B: indeg+prefix ----
__global__ void reduce2_kernel(const unsigned char* __restrict__ partialR,
                               float* __restrict__ inv_outdeg,
                               unsigned char* __restrict__ partialC,
                               int* __restrict__ indeg) {
    int blk = blockIdx.x;
    if (blk < RB) {
        int q = blk * 256 + threadIdx.x;
        if (q >= NWORDS) return;
        unsigned int s02 = 0, s13 = 0;     // packed 16-bit sums: bytes {0,2} and {1,3}
        for (int b = 0; b < HB; b++) {
            unsigned int w = *(const unsigned int*)(partialR + (size_t)b * N_NODES + q * 4);
            s02 += w & 0x00FF00FFu;
            s13 += (w >> 8) & 0x00FF00FFu;
        }
        int s0 = s02 & 0xFFFF, s2 = s02 >> 16;
        int s1 = s13 & 0xFFFF, s3 = s13 >> 16;
        int n = q * 4;
        inv_outdeg[n + 0] = 1.0f / (float)(s0 > 0 ? s0 : 1);
        inv_outdeg[n + 1] = 1.0f / (float)(s1 > 0 ? s1 : 1);
        inv_outdeg[n + 2] = 1.0f / (float)(s2 > 0 ? s2 : 1);
        inv_outdeg[n + 3] = 1.0f / (float)(s3 > 0 ? s3 : 1);
    } else {
        int q = (blk - RB) * 256 + threadIdx.x;
        if (q >= NWORDS) return;
        unsigned int r0 = 0, r1 = 0, r2 = 0, r3 = 0;     // running prefixes (fit in a byte)
        for (int b = 0; b < HB; b++) {
            unsigned int* p = (unsigned int*)(partialC + (size_t)b * N_NODES + q * 4);
            unsigned int w = *p;
            *p = (r0 & 0xFF) | ((r1 & 0xFF) << 8) | ((r2 & 0xFF) << 16) | ((r3 & 0xFF) << 24);
            r0 += w & 0xFF; r1 += (w >> 8) & 0xFF; r2 += (w >> 16) & 0xFF; r3 += (w >> 24) & 0xFF;
        }
        int n = q * 4;
        indeg[n + 0] = (int)r0;
        indeg[n + 1] = (int)r1;
        indeg[n + 2] = (int)r2;
        indeg[n + 3] = (int)r3;
    }
}

// ---------------- prefix scan of PADDED indeg -> offs (exclusive) ----------------
__global__ void scan1_kernel(const int* __restrict__ indeg, int* __restrict__ bsum) {
    __shared__ int s[SCAN_BLK];
    int i = blockIdx.x * SCAN_BLK + threadIdx.x;
    s[threadIdx.x] = (i < N_NODES) ? pad_burst(indeg[i]) : 0;
    __syncthreads();
    for (int o = SCAN_BLK / 2; o > 0; o >>= 1) {
        if (threadIdx.x < o) s[threadIdx.x] += s[threadIdx.x + o];
        __syncthreads();
    }
    if (threadIdx.x == 0) bsum[blockIdx.x] = s[0];
}

__global__ void scan2_kernel(int* __restrict__ bsum) {   // single block of 512
    __shared__ int s[512];
    int t = threadIdx.x;
    s[t] = (t < NBLK) ? bsum[t] : 0;
    __syncthreads();
    for (int o = 1; o < 512; o <<= 1) {
        int v = (t >= o) ? s[t - o] : 0;
        __syncthreads();
        s[t] += v;
        __syncthreads();
    }
    if (t < NBLK) bsum[t] = (t == 0) ? 0 : s[t - 1];     // exclusive
}

// ---------------- scan3: offs (exclusive) + write DUMMY into the <=15 pad slots per node ----
__global__ void scan3_kernel(const int* __restrict__ indeg, const int* __restrict__ bsum,
                             int* __restrict__ offs, int* __restrict__ csc_row) {
    __shared__ int s[SCAN_BLK];
    int t = threadIdx.x;
    int i = blockIdx.x * SCAN_BLK + t;
    int d = (i < N_NODES) ? indeg[i] : 0;
    int v = pad_burst(d);
    s[t] = v;
    __syncthreads();
    for (int o = 1; o < SCAN_BLK; o <<= 1) {
        int u = (t >= o) ? s[t - o] : 0;
        __syncthreads();
        s[t] += u;
        __syncthreads();
    }
    if (i < N_NODES) {
        int base = bsum[blockIdx.x] + s[t] - v;          // exclusive
        offs[i] = base;
        for (int p = base + d; p < base + v; p++) csc_row[p] = DUMMY;   // pad tail only
    }
}

// ---------------- CSC fill: LDS byte rank counters seeded with prefix base ----------------
__global__ void place_kernel(const int* __restrict__ row, const int* __restrict__ col,
                             const int* __restrict__ offs,
                             const unsigned char* __restrict__ pbase,
                             int* __restrict__ csc_row) {
    __shared__ unsigned int cnt[NWORDS];
    int b = blockIdx.x;
    int t = threadIdx.x;                   // 1024 threads
    const unsigned int* src = (const unsigned int*)(pbase + (size_t)b * N_NODES);
    for (int i = t; i < NWORDS; i += 1024) cnt[i] = src[i];   // seed with prefix-base bytes
    __syncthreads();
    for (int i = t; i < SLICE; i += 1024) {
        int e = b * SLICE + i;
        int c = col[e];
        int sh = (c & 3) * 8;
        unsigned int old = atomicAdd(&cnt[c >> 2], 1u << sh);
        int pos = (int)((old >> sh) & 0xFF);               // prefix-base + in-block rank
        csc_row[offs[c] + pos] = row[e];
    }
}

// ---------------- fused: s0 = fp16(probes*inv_od), probe-sign pack, dummy-row zero ----------
__global__ void s0pack_kernel(const float* __restrict__ probes, const float* __restrict__ inv_outdeg,
                              _Float16* __restrict__ s0h, unsigned int* __restrict__ pbits,
                              unsigned int* __restrict__ a8, unsigned int* __restrict__ b8) {
    int gid = blockIdx.x * blockDim.x + threadIdx.x;   // [0, N*8)
    if (gid < 16)      reinterpret_cast<unsigned int*>(s0h + (size_t)DUMMY * N_PROBES)[gid] = 0u;
    else if (gid < 24) a8[(size_t)DUMMY * 8 + (gid - 16)] = 0u;
    else if (gid < 32) b8[(size_t)DUMMY * 8 + (gid - 24)] = 0u;
    int n = gid >> 3;
    int j = (gid & 7) << 2;
    float iv = inv_outdeg[n];
    const float4 p = *reinterpret_cast<const float4*>(probes + (size_t)n * N_PROBES + j);
    half4 h;
    h[0] = (_Float16)(p.x * iv); h[1] = (_Float16)(p.y * iv);
    h[2] = (_Float16)(p.z * iv); h[3] = (_Float16)(p.w * iv);
    *reinterpret_cast<half4*>(s0h + (size_t)n * N_PROBES + j) = h;
    unsigned int b4 = (p.x < 0.f ? 1u : 0u) | (p.y < 0.f ? 2u : 0u) |
                      (p.z < 0.f ? 4u : 0u) | (p.w < 0.f ? 8u : 0u);
    unsigned int bits = b4 << j;
    bits |= __shfl_xor(bits, 1, 8);
    bits |= __shfl_xor(bits, 2, 8);
    bits |= __shfl_xor(bits, 4, 8);
    if ((gid & 7) == 0) pbits[n] = bits;
}

// ---------------- fused gather + rescale + Hutchinson diag ----------------
// R6/R8 structure (best-measured: simple burst-16 + one-burst-ahead plain index prefetch,
// no launch_bounds, bijective XCD swizzle). NEW this round: STATE loads are non-temporal.
// Rationale: state reads have ~0% L1 reuse (6250 random requests/CU over 100K rows), so
// L1 bypass loses nothing; if nt requests don't occupy L1/TCP MSHRs, per-CU outstanding-
// miss concurrency rises past the ~65 cap that pins the step at 18.3 us (measured fit).
// Index loads stay PLAIN (16x L1 reuse — R5 lesson). Stores stay PLAIN (R9 lesson).
template <bool IN8>
__global__ void gather_kernel(const int* __restrict__ offs, const int* __restrict__ indeg,
                              const int* __restrict__ csc_row,
                              const void* __restrict__ s_cur,
                              const unsigned int* __restrict__ pbits,
                              const float* __restrict__ inv_outdeg,
                              unsigned int* __restrict__ s_new, float* __restrict__ diag_row) {
    // bijective XCD swizzle (nwg=3125: q=390, r=5) — guide §5 m204 variant
    int bid = blockIdx.x;
    int xcd = bid & 7;
    int idx = bid >> 3;
    int swz = (xcd < GR ? xcd * (GQ + 1) : GR * (GQ + 1) + (xcd - GR) * GQ) + idx;
    int gid = swz * 256 + threadIdx.x;                 // [0, N*8) exact
    int n = gid >> 3;
    int lane = gid & 7;
    int start = offs[n];
    int pcnt  = pad_burst(indeg[n]);                   // multiple of BURST
    float inv = inv_outdeg[n];
    float4 acc = make_float4(0.f, 0.f, 0.f, 0.f);

    const _Float16*     h_base = (const _Float16*)s_cur;
    const unsigned int* q_base = (const unsigned int*)s_cur;

    int r[BURST];
    if (pcnt > 0) {
#pragma unroll
        for (int u = 0; u < BURST; u++) r[u] = csc_row[start + u];
    }
    for (int q = 0; q < pcnt; q += BURST) {
        // issue BURST independent state loads (non-temporal: no L1 reuse, dodge MSHR cap)
        half4        vh[BURST];
        unsigned int vq[BURST];
#pragma unroll
        for (int u = 0; u < BURST; u++) {
            if (IN8) vq[u] = __builtin_nontemporal_load(&q_base[(size_t)r[u] * 8 + lane]);
            else     vh[u] = *reinterpret_cast<const half4*>(h_base + (size_t)r[u] * N_PROBES + lane * 4);
        }
        // prefetch next burst's indices while state loads are in flight (plain: L1-cached)
        int r2[BURST];
        if (q + BURST < pcnt) {
#pragma unroll
            for (int u = 0; u < BURST; u++) r2[u] = csc_row[start + q + BURST + u];
        }
#pragma unroll
        for (int u = 0; u < BURST; u++) {
            if (IN8) {
                float2v lo = __builtin_amdgcn_cvt_pk_f32_fp8((int)vq[u], false);
                float2v hi = __builtin_amdgcn_cvt_pk_f32_fp8((int)vq[u], true);
                acc.x += lo[0]; acc.y += lo[1]; acc.z += hi[0]; acc.w += hi[1];
            } else {
                acc.x += (float)vh[u][0]; acc.y += (float)vh[u][1];
                acc.z += (float)vh[u][2]; acc.w += (float)vh[u][3];
            }
        }
#pragma unroll
        for (int u = 0; u < BURST; u++) r[u] = r2[u];
    }

    // acc = P_k[n] fragment (fp32). Write pre-scaled fp8 row for next step (plain store).
    int pk = 0;
    pk = __builtin_amdgcn_cvt_pk_fp8_f32(acc.x * inv, acc.y * inv, pk, false);
    pk = __builtin_amdgcn_cvt_pk_fp8_f32(acc.z * inv, acc.w * inv, pk, true);
    s_new[(size_t)n * 8 + lane] = (unsigned int)pk;

    // Hutchinson dot via packed probe signs (probes are exactly ±1)
    unsigned int bits = pbits[n] >> (lane << 2);
    float d0 = (bits & 1u) ? -acc.x : acc.x;
    float d1 = (bits & 2u) ? -acc.y : acc.y;
    float d2 = (bits & 4u) ? -acc.z : acc.z;
    float d3 = (bits & 8u) ? -acc.w : acc.w;
    float dot = d0 + d1 + d2 + d3;
    dot += __shfl_xor(dot, 4, 8);
    dot += __shfl_xor(dot, 2, 8);
    dot += __shfl_xor(dot, 1, 8);
    if (lane == 0) diag_row[n] = dot * (1.0f / (float)N_PROBES);
}

// ---------------- out[n] = diags[n,:] @ W^T + b ----------------
__global__ void out_kernel(const float* __restrict__ diags, const float* __restrict__ W,
                           const float* __restrict__ b, float* __restrict__ out) {
    int n = blockIdx.x * blockDim.x + threadIdx.x;
    if (n >= N_NODES) return;
    float d[WALK_LEN];
#pragma unroll
    for (int k = 0; k < WALK_LEN; k++) d[k] = diags[(size_t)k * N_NODES + n];
    float o[OUT_DIM];
#pragma unroll
    for (int j = 0; j < OUT_DIM; j++) {
        float acc = b[j];
#pragma unroll
        for (int k = 0; k < WALK_LEN; k++) acc += d[k] * W[j * WALK_LEN + k];
        o[j] = acc;
    }
    float4* outp = reinterpret_cast<float4*>(out + (size_t)n * OUT_DIM);
    outp[0] = make_float4(o[0], o[1], o[2], o[3]);
    outp[1] = make_float4(o[4], o[5], o[6], o[7]);
}

extern "C" void kernel_launch(void* const* d_in, const int* in_sizes, int n_in,
                              void* d_out, int out_size, void* d_ws, size_t ws_size,
                              hipStream_t stream) {
    const int*   edge_index = (const int*)d_in[0];
    const int*   row    = edge_index;
    const int*   col    = edge_index + N_EDGES;
    const float* probes = (const float*)d_in[2];
    const float* W      = (const float*)d_in[3];
    const float* b      = (const float*)d_in[4];
    float*       out    = (float*)d_out;

    // workspace carve-up (256B aligned)
    char* ws = (char*)d_ws;
    size_t off = 0;
    auto carve = [&](size_t bytes) -> void* {
        void* p = ws + off;
        off += (bytes + 255) & ~(size_t)255;
        return p;
    };
    int*           indeg    = (int*)          carve((size_t)N_NODES * 4);              // 400 KB
    int*           offs     = (int*)          carve((size_t)N_NODES * 4);              // 400 KB
    float*         inv_od   = (float*)        carve((size_t)N_NODES * 4);              // 400 KB
    int*           bsum     = (int*)          carve((size_t)NBLK * 4);                 // ~1.6 KB
    unsigned char* partialR = (unsigned char*)carve((size_t)HB * N_NODES);             // 12.8 MB
    unsigned char* partialC = (unsigned char*)carve((size_t)HB * N_NODES);             // 12.8 MB
    int*           csc_row  = (int*)          carve((size_t)CSC_CAP * 4);              // 12.4 MB
    _Float16*      s0h      = (_Float16*)     carve((size_t)(N_NODES + 1) * N_PROBES * 2); // 6.4 MB
    unsigned int*  bufA8    = (unsigned int*) carve((size_t)(N_NODES + 1) * 32);       // 3.2 MB
    unsigned int*  bufB8    = (unsigned int*) carve((size_t)(N_NODES + 1) * 32);       // 3.2 MB
    float*         diags    = (float*)        carve((size_t)WALK_LEN * N_NODES * 4);   // 6.4 MB
    unsigned int*  pbits    = (unsigned int*) carve((size_t)N_NODES * 4);              // 400 KB

    const int B = 256;
    // ---- build CSC + inv_outdeg: fused hists (256 blocks), fused reduces ----
    hist2_kernel<<<2 * HB, 1024, 0, stream>>>(row, col, partialR, partialC);
    reduce2_kernel<<<2 * RB, B, 0, stream>>>(partialR, inv_od, partialC, indeg);
    scan1_kernel<<<NBLK, SCAN_BLK, 0, stream>>>(indeg, bsum);
    scan2_kernel<<<1, 512, 0, stream>>>(bsum);
    scan3_kernel<<<NBLK, SCAN_BLK, 0, stream>>>(indeg, bsum, offs, csc_row);
    place_kernel<<<HB, 1024, 0, stream>>>(row, col, offs, partialC, csc_row);

    // ---- fused s0 (fp16) + probe-sign pack + dummy-row zero ----
    s0pack_kernel<<<(N_NODES * 8 + B - 1) / B, B, 0, stream>>>(probes, inv_od, s0h,
                                                               pbits, bufA8, bufB8);

    // ---- 16 fused transition + diag steps: step 0 fp16->fp8, steps 1..15 fp8->fp8 ----
    gather_kernel<false><<<GGRID, B, 0, stream>>>(offs, indeg, csc_row, (const void*)s0h,
                                                  pbits, inv_od, bufA8, diags);
    const unsigned int* cur = bufA8;
    for (int k = 1; k < WALK_LEN; k++) {
        unsigned int* nxt = (k & 1) ? bufB8 : bufA8;
        gather_kernel<true><<<GGRID, B, 0, stream>>>(offs, indeg, csc_row, (const void*)cur,
                                                     pbits, inv_od, nxt, diags + (size_t)k * N_NODES);
        cur = nxt;
    }

    out_kernel<<<(N_NODES + B - 1) / B, B, 0, stream>>>(diags, W, b, out);
}

// Round 12
// 385.227 us; speedup vs baseline: 1.6009x; 1.6009x over previous
//
#include <hip/hip_runtime.h>

#define N_NODES   100000
#define N_EDGES   1600000
#define WALK_LEN  16
#define OUT_DIM   8
#define N_PROBES  32

#define SCAN_BLK  256
#define NBLK      ((N_NODES + SCAN_BLK - 1) / SCAN_BLK)   // 391

// ---- LDS byte-counter build parameters ----
#define HB        128                      // histogram blocks per array (row/col)
#define SLICE     (N_EDGES / HB)           // 12500 edges per block (exact)
#define NWORDS    (N_NODES / 4)            // 25000 packed uints = 100 KB LDS
#define RB        ((NWORDS + 255) / 256)   // reduce blocks per half

// ---- adjacency padding: every list rounded up to multiple of 16 (burst) ----
#define BURST     16
#define DUMMY     N_NODES                  // dummy source row (always zero)
#define CSC_CAP   (N_EDGES + (BURST - 1) * N_NODES)   // 3.1M padded entries

typedef _Float16 half4 __attribute__((ext_vector_type(4)));
typedef float float2v __attribute__((ext_vector_type(2)));

__device__ __forceinline__ int pad_burst(int x) { return (x + BURST - 1) & ~(BURST - 1); }

// ---------------- fused per-block byte-packed histograms: row -> partialR, col -> partialC ----
__global__ void hist2_kernel(const int* __restrict__ row, const int* __restrict__ col,
                             unsigned char* __restrict__ partialR,
                             unsigned char* __restrict__ partialC) {
    __shared__ unsigned int cnt[NWORDS];
    int blk = blockIdx.x;
    const int* arr = (blk < HB) ? row : col;
    unsigned char* partial = (blk < HB) ? partialR : partialC;
    int b = (blk < HB) ? blk : blk - HB;
    int t = threadIdx.x;                   // 1024 threads
    for (int i = t; i < NWORDS; i += 1024) cnt[i] = 0;
    __syncthreads();
    const int* a = arr + b * SLICE;
    for (int i = t; i < SLICE; i += 1024) {
        int v = a[i];
        atomicAdd(&cnt[v >> 2], 1u << ((v & 3) * 8));
    }
    __syncthreads();
    unsigned int* dst = (unsigned int*)(partial + (size_t)b * N_NODES);
    for (int i = t; i < NWORDS; i += 1024) dst[i] = cnt[i];
}

// ---------------- fused reduces: half A: outdeg->inv (packed dual counters); half B: indeg+prefix ----
__global__ void reduce2_kernel(const unsigned char* __restrict__ partialR,
                               float* __restrict__ inv_outdeg,
                               unsigned char* __restrict__ partialC,
                               int* __restrict__ indeg) {
    int blk = blockIdx.x;
    if (blk < RB) {
        int q = blk * 256 + threadIdx.x;
        if (q >= NWORDS) return;
        unsigned int s02 = 0, s13 = 0;     // packed 16-bit sums: bytes {0,2} and {1,3}
        for (int b = 0; b < HB; b++) {
            unsigned int w = *(const unsigned int*)(partialR + (size_t)b * N_NODES + q * 4);
            s02 += w & 0x00FF00FFu;
            s13 += (w >> 8) & 0x00FF00FFu;
        }
        int s0 = s02 & 0xFFFF, s2 = s02 >> 16;
        int s1 = s13 & 0xFFFF, s3 = s13 >> 16;
        int n = q * 4;
        inv_outdeg[n + 0] = 1.0f / (float)(s0 > 0 ? s0 : 1);
        inv_outdeg[n + 1] = 1.0f / (float)(s1 > 0 ? s1 : 1);
        inv_outdeg[n + 2] = 1.0f / (float)(s2 > 0 ? s2 : 1);
        inv_outdeg[n + 3] = 1.0f / (float)(s3 > 0 ? s3 : 1);
    } else {
        int q = (blk - RB) * 256 + threadIdx.x;
        if (q >= NWORDS) return;
        unsigned int r0 = 0, r1 = 0, r2 = 0, r3 = 0;     // running prefixes (fit in a byte)
        for (int b = 0; b < HB; b++) {
            unsigned int* p = (unsigned int*)(partialC + (size_t)b * N_NODES + q * 4);
            unsigned int w = *p;
            *p = (r0 & 0xFF) | ((r1 & 0xFF) << 8) | ((r2 & 0xFF) << 16) | ((r3 & 0xFF) << 24);
            r0 += w & 0xFF; r1 += (w >> 8) & 0xFF; r2 += (w >> 16) & 0xFF; r3 += (w >> 24) & 0xFF;
        }
        int n = q * 4;
        indeg[n + 0] = (int)r0;
        indeg[n + 1] = (int)r1;
        indeg[n + 2] = (int)r2;
        indeg[n + 3] = (int)r3;
    }
}

// ---------------- prefix scan of PADDED indeg -> offs (exclusive) ----------------
__global__ void scan1_kernel(const int* __restrict__ indeg, int* __restrict__ bsum) {
    __shared__ int s[SCAN_BLK];
    int i = blockIdx.x * SCAN_BLK + threadIdx.x;
    s[threadIdx.x] = (i < N_NODES) ? pad_burst(indeg[i]) : 0;
    __syncthreads();
    for (int o = SCAN_BLK / 2; o > 0; o >>= 1) {
        if (threadIdx.x < o) s[threadIdx.x] += s[threadIdx.x + o];
        __syncthreads();
    }
    if (threadIdx.x == 0) bsum[blockIdx.x] = s[0];
}

__global__ void scan2_kernel(int* __restrict__ bsum) {   // single block of 512
    __shared__ int s[512];
    int t = threadIdx.x;
    s[t] = (t < NBLK) ? bsum[t] : 0;
    __syncthreads();
    for (int o = 1; o < 512; o <<= 1) {
        int v = (t >= o) ? s[t - o] : 0;
        __syncthreads();
        s[t] += v;
        __syncthreads();
    }
    if (t < NBLK) bsum[t] = (t == 0) ? 0 : s[t - 1];     // exclusive
}

// ---------------- scan3: offs (exclusive) + write DUMMY into the <=15 pad slots per node ----
__global__ void scan3_kernel(const int* __restrict__ indeg, const int* __restrict__ bsum,
                             int* __restrict__ offs, int* __restrict__ csc_row) {
    __shared__ int s[SCAN_BLK];
    int t = threadIdx.x;
    int i = blockIdx.x * SCAN_BLK + t;
    int d = (i < N_NODES) ? indeg[i] : 0;
    int v = pad_burst(d);
    s[t] = v;
    __syncthreads();
    for (int o = 1; o < SCAN_BLK; o <<= 1) {
        int u = (t >= o) ? s[t - o] : 0;
        __syncthreads();
        s[t] += u;
        __syncthreads();
    }
    if (i < N_NODES) {
        int base = bsum[blockIdx.x] + s[t] - v;          // exclusive
        offs[i] = base;
        for (int p = base + d; p < base + v; p++) csc_row[p] = DUMMY;   // pad tail only
    }
}

// ---------------- CSC fill: LDS byte rank counters seeded with prefix base ----------------
__global__ void place_kernel(const int* __restrict__ row, const int* __restrict__ col,
                             const int* __restrict__ offs,
                             const unsigned char* __restrict__ pbase,
                             int* __restrict__ csc_row) {
    __shared__ unsigned int cnt[NWORDS];
    int b = blockIdx.x;
    int t = threadIdx.x;                   // 1024 threads
    const unsigned int* src = (const unsigned int*)(pbase + (size_t)b * N_NODES);
    for (int i = t; i < NWORDS; i += 1024) cnt[i] = src[i];   // seed with prefix-base bytes
    __syncthreads();
    for (int i = t; i < SLICE; i += 1024) {
        int e = b * SLICE + i;
        int c = col[e];
        int sh = (c & 3) * 8;
        unsigned int old = atomicAdd(&cnt[c >> 2], 1u << sh);
        int pos = (int)((old >> sh) & 0xFF);               // prefix-base + in-block rank
        csc_row[offs[c] + pos] = row[e];
    }
}

// ---------------- fused: s0 = fp16(probes*inv_od), probe-sign pack, dummy-row zero ----------
__global__ void s0pack_kernel(const float* __restrict__ probes, const float* __restrict__ inv_outdeg,
                              _Float16* __restrict__ s0h, unsigned int* __restrict__ pbits,
                              unsigned int* __restrict__ a8, unsigned int* __restrict__ b8) {
    int gid = blockIdx.x * blockDim.x + threadIdx.x;   // [0, N*8)
    if (gid < 16)      reinterpret_cast<unsigned int*>(s0h + (size_t)DUMMY * N_PROBES)[gid] = 0u;
    else if (gid < 24) a8[(size_t)DUMMY * 8 + (gid - 16)] = 0u;
    else if (gid < 32) b8[(size_t)DUMMY * 8 + (gid - 24)] = 0u;
    int n = gid >> 3;
    int j = (gid & 7) << 2;
    float iv = inv_outdeg[n];
    const float4 p = *reinterpret_cast<const float4*>(probes + (size_t)n * N_PROBES + j);
    half4 h;
    h[0] = (_Float16)(p.x * iv); h[1] = (_Float16)(p.y * iv);
    h[2] = (_Float16)(p.z * iv); h[3] = (_Float16)(p.w * iv);
    *reinterpret_cast<half4*>(s0h + (size_t)n * N_PROBES + j) = h;
    unsigned int b4 = (p.x < 0.f ? 1u : 0u) | (p.y < 0.f ? 2u : 0u) |
                      (p.z < 0.f ? 4u : 0u) | (p.w < 0.f ? 8u : 0u);
    unsigned int bits = b4 << j;
    bits |= __shfl_xor(bits, 1, 8);
    bits |= __shfl_xor(bits, 2, 8);
    bits |= __shfl_xor(bits, 4, 8);
    if ((gid & 7) == 0) pbits[n] = bits;
}

// ---------------- fused gather + rescale + Hutchinson diag ----------------
// R6 structure VERBATIM — the best-measured configuration (385.9 us total):
// simple burst-16 + one-burst-ahead PLAIN index prefetch (compiler software-pipelines it),
// PLAIN coalesced state loads (8 lanes/node share one 64B line -> 1 request; NT broke
// this into 8, R10), plain stores (NT forfeits write-allocate, R9), no launch_bounds
// (caps below the ~90-VGPR live set spill the pipeline, R5/R7), no swizzle (null, R8).
// This sits at the measured latency-cap floor: ~6250 lines/CU/step x ~450cy / ~64
// outstanding ~= 18 us/step.
template <bool IN8>
__global__ void gather_kernel(const int* __restrict__ offs, const int* __restrict__ indeg,
                              const int* __restrict__ csc_row,
                              const void* __restrict__ s_cur,
                              const unsigned int* __restrict__ pbits,
                              const float* __restrict__ inv_outdeg,
                              unsigned int* __restrict__ s_new, float* __restrict__ diag_row) {
    int gid = blockIdx.x * blockDim.x + threadIdx.x;   // [0, N*8) exact
    int n = gid >> 3;
    int lane = gid & 7;
    int start = offs[n];
    int pcnt  = pad_burst(indeg[n]);                   // multiple of BURST
    float inv = inv_outdeg[n];
    float4 acc = make_float4(0.f, 0.f, 0.f, 0.f);

    const _Float16*     h_base = (const _Float16*)s_cur;
    const unsigned int* q_base = (const unsigned int*)s_cur;

    int r[BURST];
    if (pcnt > 0) {
#pragma unroll
        for (int u = 0; u < BURST; u++) r[u] = csc_row[start + u];
    }
    for (int q = 0; q < pcnt; q += BURST) {
        // issue BURST independent state loads
        half4        vh[BURST];
        unsigned int vq[BURST];
#pragma unroll
        for (int u = 0; u < BURST; u++) {
            if (IN8) vq[u] = q_base[(size_t)r[u] * 8 + lane];
            else     vh[u] = *reinterpret_cast<const half4*>(h_base + (size_t)r[u] * N_PROBES + lane * 4);
        }
        // prefetch next burst's indices while state loads are in flight
        int r2[BURST];
        if (q + BURST < pcnt) {
#pragma unroll
            for (int u = 0; u < BURST; u++) r2[u] = csc_row[start + q + BURST + u];
        }
#pragma unroll
        for (int u = 0; u < BURST; u++) {
            if (IN8) {
                float2v lo = __builtin_amdgcn_cvt_pk_f32_fp8((int)vq[u], false);
                float2v hi = __builtin_amdgcn_cvt_pk_f32_fp8((int)vq[u], true);
                acc.x += lo[0]; acc.y += lo[1]; acc.z += hi[0]; acc.w += hi[1];
            } else {
                acc.x += (float)vh[u][0]; acc.y += (float)vh[u][1];
                acc.z += (float)vh[u][2]; acc.w += (float)vh[u][3];
            }
        }
#pragma unroll
        for (int u = 0; u < BURST; u++) r[u] = r2[u];
    }

    // acc = P_k[n] fragment (fp32). Write pre-scaled fp8 row for next step.
    int pk = 0;
    pk = __builtin_amdgcn_cvt_pk_fp8_f32(acc.x * inv, acc.y * inv, pk, false);
    pk = __builtin_amdgcn_cvt_pk_fp8_f32(acc.z * inv, acc.w * inv, pk, true);
    s_new[(size_t)n * 8 + lane] = (unsigned int)pk;

    // Hutchinson dot via packed probe signs (probes are exactly ±1)
    unsigned int bits = pbits[n] >> (lane << 2);
    float d0 = (bits & 1u) ? -acc.x : acc.x;
    float d1 = (bits & 2u) ? -acc.y : acc.y;
    float d2 = (bits & 4u) ? -acc.z : acc.z;
    float d3 = (bits & 8u) ? -acc.w : acc.w;
    float dot = d0 + d1 + d2 + d3;
    dot += __shfl_xor(dot, 4, 8);
    dot += __shfl_xor(dot, 2, 8);
    dot += __shfl_xor(dot, 1, 8);
    if (lane == 0) diag_row[n] = dot * (1.0f / (float)N_PROBES);
}

// ---------------- out[n] = diags[n,:] @ W^T + b ----------------
__global__ void out_kernel(const float* __restrict__ diags, const float* __restrict__ W,
                           const float* __restrict__ b, float* __restrict__ out) {
    int n = blockIdx.x * blockDim.x + threadIdx.x;
    if (n >= N_NODES) return;
    float d[WALK_LEN];
#pragma unroll
    for (int k = 0; k < WALK_LEN; k++) d[k] = diags[(size_t)k * N_NODES + n];
    float o[OUT_DIM];
#pragma unroll
    for (int j = 0; j < OUT_DIM; j++) {
        float acc = b[j];
#pragma unroll
        for (int k = 0; k < WALK_LEN; k++) acc += d[k] * W[j * WALK_LEN + k];
        o[j] = acc;
    }
    float4* outp = reinterpret_cast<float4*>(out + (size_t)n * OUT_DIM);
    outp[0] = make_float4(o[0], o[1], o[2], o[3]);
    outp[1] = make_float4(o[4], o[5], o[6], o[7]);
}

extern "C" void kernel_launch(void* const* d_in, const int* in_sizes, int n_in,
                              void* d_out, int out_size, void* d_ws, size_t ws_size,
                              hipStream_t stream) {
    const int*   edge_index = (const int*)d_in[0];
    const int*   row    = edge_index;
    const int*   col    = edge_index + N_EDGES;
    const float* probes = (const float*)d_in[2];
    const float* W      = (const float*)d_in[3];
    const float* b      = (const float*)d_in[4];
    float*       out    = (float*)d_out;

    // workspace carve-up (256B aligned)
    char* ws = (char*)d_ws;
    size_t off = 0;
    auto carve = [&](size_t bytes) -> void* {
        void* p = ws + off;
        off += (bytes + 255) & ~(size_t)255;
        return p;
    };
    int*           indeg    = (int*)          carve((size_t)N_NODES * 4);              // 400 KB
    int*           offs     = (int*)          carve((size_t)N_NODES * 4);              // 400 KB
    float*         inv_od   = (float*)        carve((size_t)N_NODES * 4);              // 400 KB
    int*           bsum     = (int*)          carve((size_t)NBLK * 4);                 // ~1.6 KB
    unsigned char* partialR = (unsigned char*)carve((size_t)HB * N_NODES);             // 12.8 MB
    unsigned char* partialC = (unsigned char*)carve((size_t)HB * N_NODES);             // 12.8 MB
    int*           csc_row  = (int*)          carve((size_t)CSC_CAP * 4);              // 12.4 MB
    _Float16*      s0h      = (_Float16*)     carve((size_t)(N_NODES + 1) * N_PROBES * 2); // 6.4 MB
    unsigned int*  bufA8    = (unsigned int*) carve((size_t)(N_NODES + 1) * 32);       // 3.2 MB
    unsigned int*  bufB8    = (unsigned int*) carve((size_t)(N_NODES + 1) * 32);       // 3.2 MB
    float*         diags    = (float*)        carve((size_t)WALK_LEN * N_NODES * 4);   // 6.4 MB
    unsigned int*  pbits    = (unsigned int*) carve((size_t)N_NODES * 4);              // 400 KB

    const int B = 256;
    // ---- build CSC + inv_outdeg: fused hists (256 blocks), fused reduces ----
    hist2_kernel<<<2 * HB, 1024, 0, stream>>>(row, col, partialR, partialC);
    reduce2_kernel<<<2 * RB, B, 0, stream>>>(partialR, inv_od, partialC, indeg);
    scan1_kernel<<<NBLK, SCAN_BLK, 0, stream>>>(indeg, bsum);
    scan2_kernel<<<1, 512, 0, stream>>>(bsum);
    scan3_kernel<<<NBLK, SCAN_BLK, 0, stream>>>(indeg, bsum, offs, csc_row);
    place_kernel<<<HB, 1024, 0, stream>>>(row, col, offs, partialC, csc_row);

    // ---- fused s0 (fp16) + probe-sign pack + dummy-row zero ----
    s0pack_kernel<<<(N_NODES * 8 + B - 1) / B, B, 0, stream>>>(probes, inv_od, s0h,
                                                               pbits, bufA8, bufB8);

    // ---- 16 fused transition + diag steps: step 0 fp16->fp8, steps 1..15 fp8->fp8 ----
    const int GRID = (N_NODES * 8 + B - 1) / B;
    gather_kernel<false><<<GRID, B, 0, stream>>>(offs, indeg, csc_row, (const void*)s0h,
                                                 pbits, inv_od, bufA8, diags);
    const unsigned int* cur = bufA8;
    for (int k = 1; k < WALK_LEN; k++) {
        unsigned int* nxt = (k & 1) ? bufB8 : bufA8;
        gather_kernel<true><<<GRID, B, 0, stream>>>(offs, indeg, csc_row, (const void*)cur,
                                                    pbits, inv_od, nxt, diags + (size_t)k * N_NODES);
        cur = nxt;
    }

    out_kernel<<<(N_NODES + B - 1) / B, B, 0, stream>>>(diags, W, b, out);
}